// Round 2
// baseline (769.453 us; speedup 1.0000x reference)
//
#include <hip/hip_runtime.h>

#define DEV __device__ __forceinline__

typedef __bf16 bf16x8 __attribute__((ext_vector_type(8)));
typedef float f32x4 __attribute__((ext_vector_type(4)));
typedef float f32x2 __attribute__((ext_vector_type(2)));

constexpr int TOK = 32768;   // B*N tokens
constexpr int D   = 512;
constexpr int P   = 720;
constexpr float EPS = 1e-5f;

DEV unsigned short f2bf(float f) {
  unsigned u = __float_as_uint(f);
  u += 0x7FFFu + ((u >> 16) & 1u);   // RNE (normals; inputs are finite randoms)
  return (unsigned short)(u >> 16);
}

DEV void g2lds16(const void* g, void* l) {
  __builtin_amdgcn_global_load_lds(
      (__attribute__((address_space(1))) void*)g,
      (__attribute__((address_space(3))) void*)l, 16, 0, 0);
}

// ---------------- W_exp [2][D][P] fp32 -> WT [2][P][D] bf16 -----------------
__global__ void wconv_kernel(const float* __restrict__ W,
                             unsigned short* __restrict__ WT) {
  __shared__ float ls[16][17];
  const int e  = blockIdx.z;
  const int d0 = blockIdx.x * 16, p0 = blockIdx.y * 16;
  const int tx = threadIdx.x, ty = threadIdx.y;
  ls[ty][tx] = W[((size_t)e * D + d0 + ty) * P + p0 + tx];
  __syncthreads();
  WT[((size_t)e * P + p0 + ty) * D + d0 + tx] = f2bf(ls[tx][ty]);
}

// ---------------- classifier v2: fp32 MLP -> idx[TOK]; writes x as bf16 -----
// TM=64 tokens/block, all 128 L1-cols, BK=32, reg-blocked 4tok x 8col/thread.
// W1 tile staged in LDS; T14 prefetch (issue-early/commit-late); float2 math
// to invite v_pk_fma_f32.
__global__ __launch_bounds__(256, 2) void classifier_kernel(
    const float* __restrict__ x,
    const float* __restrict__ W1, const float* __restrict__ b1,
    const float* __restrict__ g1, const float* __restrict__ be1,
    const float* __restrict__ m1, const float* __restrict__ v1,
    const float* __restrict__ W2, const float* __restrict__ b2,
    const float* __restrict__ g2, const float* __restrict__ be2,
    const float* __restrict__ m2, const float* __restrict__ v2,
    const float* __restrict__ W3, const float* __restrict__ b3,
    unsigned short* __restrict__ xb, int* __restrict__ idx_out)
{
  constexpr int TM = 64, BK = 32;
  // union'd LDS: pass1 = xs[32][68] (8704B) + ws[32][132] (16896B) = 25600B
  //              pass2 = h1s[128][68] (34816B) + h2s[32][68] (8704B) = 43520B
  __shared__ __align__(16) char smem[43520];
  float (*xs)[68]  = (float(*)[68])smem;
  float (*ws)[132] = (float(*)[132])(smem + 8704);
  float (*h1s)[68] = (float(*)[68])smem;
  float (*h2s)[68] = (float(*)[68])(smem + 34816);

  const int tid = threadIdx.x;
  const int t0  = blockIdx.x * TM;

  // staging maps
  const int sr = tid >> 3;          // x row 0..31 (and +32)
  const int sk = (tid & 7) * 4;     // x k-chunk
  const int wk = tid >> 5;          // W1 k-row 0..7 (+8j)
  const int wc = (tid & 31) * 4;    // W1 col chunk

  // compute maps
  const int tg = tid >> 4;          // token group: tokens tg*4..+3
  const int c0 = (tid & 15) * 8;    // 8 cols

  f32x2 acc0[8], acc1[8];
  #pragma unroll
  for (int j = 0; j < 8; ++j) { acc0[j] = (f32x2)0.f; acc1[j] = (f32x2)0.f; }

  float4 px0, px1, pw0, pw1, pw2, pw3;

  auto issue = [&](int kt) {
    const int k0 = kt * BK;
    px0 = *reinterpret_cast<const float4*>(&x[(size_t)(t0 + sr) * D + k0 + sk]);
    px1 = *reinterpret_cast<const float4*>(&x[(size_t)(t0 + sr + 32) * D + k0 + sk]);
    pw0 = *reinterpret_cast<const float4*>(&W1[(size_t)(k0 + wk) * 128 + wc]);
    pw1 = *reinterpret_cast<const float4*>(&W1[(size_t)(k0 + wk + 8) * 128 + wc]);
    pw2 = *reinterpret_cast<const float4*>(&W1[(size_t)(k0 + wk + 16) * 128 + wc]);
    pw3 = *reinterpret_cast<const float4*>(&W1[(size_t)(k0 + wk + 24) * 128 + wc]);
  };
  auto commit = [&](int kt) {
    const int k0 = kt * BK;
    xs[sk + 0][sr] = px0.x; xs[sk + 1][sr] = px0.y;
    xs[sk + 2][sr] = px0.z; xs[sk + 3][sr] = px0.w;
    xs[sk + 0][sr + 32] = px1.x; xs[sk + 1][sr + 32] = px1.y;
    xs[sk + 2][sr + 32] = px1.z; xs[sk + 3][sr + 32] = px1.w;
    ushort4 u0, u1;
    u0.x = f2bf(px0.x); u0.y = f2bf(px0.y); u0.z = f2bf(px0.z); u0.w = f2bf(px0.w);
    u1.x = f2bf(px1.x); u1.y = f2bf(px1.y); u1.z = f2bf(px1.z); u1.w = f2bf(px1.w);
    *reinterpret_cast<ushort4*>(&xb[(size_t)(t0 + sr) * D + k0 + sk]) = u0;
    *reinterpret_cast<ushort4*>(&xb[(size_t)(t0 + sr + 32) * D + k0 + sk]) = u1;
    *reinterpret_cast<float4*>(&ws[wk][wc])      = pw0;
    *reinterpret_cast<float4*>(&ws[wk + 8][wc])  = pw1;
    *reinterpret_cast<float4*>(&ws[wk + 16][wc]) = pw2;
    *reinterpret_cast<float4*>(&ws[wk + 24][wc]) = pw3;
  };

  issue(0); commit(0);
  __syncthreads();

  for (int kt = 0; kt < D / BK; ++kt) {
    if (kt < D / BK - 1) issue(kt + 1);   // loads in flight during compute
    #pragma unroll
    for (int kk = 0; kk < BK; ++kk) {
      const float4 xv = *reinterpret_cast<const float4*>(&xs[kk][tg * 4]);
      const float4 wa = *reinterpret_cast<const float4*>(&ws[kk][c0]);
      const float4 wb = *reinterpret_cast<const float4*>(&ws[kk][c0 + 4]);
      f32x2 xlo; xlo[0] = xv.x; xlo[1] = xv.y;
      f32x2 xhi; xhi[0] = xv.z; xhi[1] = xv.w;
      const float wr[8] = {wa.x, wa.y, wa.z, wa.w, wb.x, wb.y, wb.z, wb.w};
      #pragma unroll
      for (int j = 0; j < 8; ++j) {
        f32x2 wv = {wr[j], wr[j]};
        acc0[j] = xlo * wv + acc0[j];
        acc1[j] = xhi * wv + acc1[j];
      }
    }
    __syncthreads();
    if (kt < D / BK - 1) { commit(kt + 1); __syncthreads(); }
  }

  // BN1 + ReLU -> h1s[c][t]   (after barrier above, xs/ws are dead)
  #pragma unroll
  for (int j = 0; j < 8; ++j) {
    const int c = c0 + j;
    const float A  = g1[c] / sqrtf(v1[c] + EPS);
    const float Bc = (b1[c] - m1[c]) * A + be1[c];
    float4 hv;
    hv.x = fmaxf(0.f, fmaf(acc0[j][0], A, Bc));
    hv.y = fmaxf(0.f, fmaf(acc0[j][1], A, Bc));
    hv.z = fmaxf(0.f, fmaf(acc1[j][0], A, Bc));
    hv.w = fmaxf(0.f, fmaf(acc1[j][1], A, Bc));
    *reinterpret_cast<float4*>(&h1s[c][tg * 4]) = hv;
  }
  __syncthreads();

  // layer 2: per thread 2 tokens x 4 cols, float2 math
  {
    const int c2 = (tid & 7) * 4;
    const int t2 = (tid >> 3) * 2;
    f32x2 a2[4];
    #pragma unroll
    for (int c = 0; c < 4; ++c) a2[c] = (f32x2)0.f;
    #pragma unroll 8
    for (int j = 0; j < 128; ++j) {
      const f32x2 h = *reinterpret_cast<const f32x2*>(&h1s[j][t2]);
      const float4 w = *reinterpret_cast<const float4*>(&W2[j * 32 + c2]);
      const float wr[4] = {w.x, w.y, w.z, w.w};
      #pragma unroll
      for (int c = 0; c < 4; ++c) {
        f32x2 wv = {wr[c], wr[c]};
        a2[c] = h * wv + a2[c];
      }
    }
    #pragma unroll
    for (int c = 0; c < 4; ++c) {
      const int cc = c2 + c;
      const float A  = g2[cc] / sqrtf(v2[cc] + EPS);
      const float Bc = (b2[cc] - m2[cc]) * A + be2[cc];
      f32x2 hv;
      hv[0] = fmaxf(0.f, fmaf(a2[c][0], A, Bc));
      hv[1] = fmaxf(0.f, fmaf(a2[c][1], A, Bc));
      *reinterpret_cast<f32x2*>(&h2s[cc][t2]) = hv;
    }
  }
  __syncthreads();

  // layer 3 + decision:  idx = (logit > 0)  [== clip(round(sigmoid),0,1)]
  if (tid < TM) {
    float logit = b3[0];
    #pragma unroll
    for (int k = 0; k < 32; ++k)
      logit = fmaf(h2s[k][tid], W3[k], logit);
    idx_out[t0 + tid] = (logit > 0.f) ? 1 : 0;
  }
}

// ---------------- expert GEMM: bf16 MFMA, both experts, per-row select ------
__global__ __launch_bounds__(256) void expert_gemm_kernel(
    const unsigned short* __restrict__ xb,   // [TOK][D] bf16 bits
    const unsigned short* __restrict__ WT,   // [2][P][D] bf16 bits
    const float* __restrict__ b_exp,         // [2][P]
    const int* __restrict__ idx,             // [TOK]
    float* __restrict__ out)                 // [TOK][P]
{
  constexpr int GM = 128, GN = 80, GK = 32;
  __shared__ __align__(16) unsigned short As[GM * GK];      // 8 KB, 64 B rows
  __shared__ __align__(16) unsigned short Bs[2 * GN * GK];  // 10 KB

  const int tid  = threadIdx.x;
  const int wave = tid >> 6;
  const int lane = tid & 63;
  const int t0 = blockIdx.x * GM;
  const int p0 = blockIdx.y * GN;

  f32x4 acc[2][2][5];
  #pragma unroll
  for (int e = 0; e < 2; ++e)
    #pragma unroll
    for (int mf = 0; mf < 2; ++mf)
      #pragma unroll
      for (int nf = 0; nf < 5; ++nf) acc[e][mf][nf] = (f32x4)(0.f);

  // staging geometry: one wave-op = 1024 B = 16 rows of 64 B
  const int srow = lane >> 2;                       // row within 16-row chunk
  const int sswz = (lane & 3) ^ ((srow >> 1) & 3);  // source chunk (XOR swizzle)

  for (int kt = 0; kt < D / GK; ++kt) {
    const int k0 = kt * GK;
    #pragma unroll
    for (int i = 0; i < 5; ++i) {
      const int c = wave + i * 4;
      if (c < 18) {
        if (c < 8) {                                   // A: 8 chunks
          const int row = c * 16 + srow;
          g2lds16(xb + (size_t)(t0 + row) * D + k0 + sswz * 8,
                  (char*)As + c * 1024);
        } else {                                       // B: 2 experts x 5 chunks
          const int cb = c - 8;
          const int e  = (cb >= 5) ? 1 : 0;
          const int bc = cb - e * 5;
          const int pr = bc * 16 + srow;
          g2lds16(WT + ((size_t)e * P + p0 + pr) * D + k0 + sswz * 8,
                  (char*)Bs + e * 5120 + bc * 1024);
        }
      }
    }
    __syncthreads();

    bf16x8 af[2];
    #pragma unroll
    for (int mf = 0; mf < 2; ++mf) {
      const int r  = wave * 32 + mf * 16 + (lane & 15);
      const int ch = (lane >> 4) ^ ((r >> 1) & 3);
      af[mf] = *(const bf16x8*)((const char*)As + r * 64 + ch * 16);
    }
    #pragma unroll
    for (int e = 0; e < 2; ++e) {
      #pragma unroll
      for (int nf = 0; nf < 5; ++nf) {
        const int pr = nf * 16 + (lane & 15);
        const int ch = (lane >> 4) ^ ((pr >> 1) & 3);
        bf16x8 bfrag = *(const bf16x8*)((const char*)Bs + e * 5120 + pr * 64 + ch * 16);
        #pragma unroll
        for (int mf = 0; mf < 2; ++mf)
          acc[e][mf][nf] = __builtin_amdgcn_mfma_f32_16x16x32_bf16(
              af[mf], bfrag, acc[e][mf][nf], 0, 0, 0);
      }
    }
    __syncthreads();
  }

  // epilogue: per-row expert select + bias, store fp32
  const int col = lane & 15;
  const int rg  = lane >> 4;
  int er[2][4];
  #pragma unroll
  for (int mf = 0; mf < 2; ++mf)
    #pragma unroll
    for (int j = 0; j < 4; ++j)
      er[mf][j] = idx[t0 + wave * 32 + mf * 16 + rg * 4 + j];

  #pragma unroll
  for (int nf = 0; nf < 5; ++nf) {
    const int p = p0 + nf * 16 + col;
    const float be0 = b_exp[p];
    const float be1v = b_exp[P + p];
    #pragma unroll
    for (int mf = 0; mf < 2; ++mf) {
      #pragma unroll
      for (int j = 0; j < 4; ++j) {
        const int row = wave * 32 + mf * 16 + rg * 4 + j;
        const float v = er[mf][j] ? (acc[1][mf][nf][j] + be1v)
                                  : (acc[0][mf][nf][j] + be0);
        out[(size_t)(t0 + row) * P + p] = v;
      }
    }
  }
}

extern "C" void kernel_launch(void* const* d_in, const int* in_sizes, int n_in,
                              void* d_out, int out_size, void* d_ws, size_t ws_size,
                              hipStream_t stream) {
  const float* x     = (const float*)d_in[0];
  const float* W_exp = (const float*)d_in[1];
  const float* b_exp = (const float*)d_in[2];
  const float* W1 = (const float*)d_in[3];
  const float* b1 = (const float*)d_in[4];
  const float* g1 = (const float*)d_in[5];
  const float* be1 = (const float*)d_in[6];
  const float* m1 = (const float*)d_in[7];
  const float* v1 = (const float*)d_in[8];
  const float* W2 = (const float*)d_in[9];
  const float* b2 = (const float*)d_in[10];
  const float* g2 = (const float*)d_in[11];
  const float* be2 = (const float*)d_in[12];
  const float* m2 = (const float*)d_in[13];
  const float* v2 = (const float*)d_in[14];
  const float* W3 = (const float*)d_in[15];
  const float* b3 = (const float*)d_in[16];
  float* out = (float*)d_out;

  unsigned short* xb = (unsigned short*)d_ws;                       // 32 MB
  unsigned short* WT = (unsigned short*)((char*)d_ws + (size_t)TOK * D * 2);
  int* idx = (int*)((char*)d_ws + (size_t)TOK * D * 2 + (size_t)2 * P * D * 2);

  hipLaunchKernelGGL(wconv_kernel, dim3(D / 16, P / 16, 2), dim3(16, 16),
                     0, stream, W_exp, WT);
  hipLaunchKernelGGL(classifier_kernel, dim3(TOK / 64), dim3(256), 0, stream,
                     x, W1, b1, g1, be1, m1, v1, W2, b2, g2, be2, m2, v2, W3, b3,
                     xb, idx);
  hipLaunchKernelGGL(expert_gemm_kernel, dim3(TOK / 128, P / 80), dim3(256),
                     0, stream, xb, WT, b_exp, idx, out);
}

// Round 3
// 209.617 us; speedup vs baseline: 3.6708x; 3.6708x over previous
//
#include <hip/hip_runtime.h>

#define DEV __device__ __forceinline__

typedef __bf16 bf16x8 __attribute__((ext_vector_type(8)));
typedef float f32x4 __attribute__((ext_vector_type(4)));
typedef float f32x2 __attribute__((ext_vector_type(2)));

constexpr int TOK = 32768;   // B*N tokens
constexpr int D   = 512;
constexpr int P   = 720;
constexpr float EPS = 1e-5f;

DEV unsigned short f2bf(float f) {
  unsigned u = __float_as_uint(f);
  u += 0x7FFFu + ((u >> 16) & 1u);   // RNE (normals; inputs are finite randoms)
  return (unsigned short)(u >> 16);
}

DEV void g2lds16(const void* g, void* l) {
  __builtin_amdgcn_global_load_lds(
      (__attribute__((address_space(1))) void*)g,
      (__attribute__((address_space(3))) void*)l, 16, 0, 0);
}

// ---------------- W_exp [2][D][P] fp32 -> WT [2][P][D] bf16 -----------------
__global__ void wconv_kernel(const float* __restrict__ W,
                             unsigned short* __restrict__ WT) {
  __shared__ float ls[16][17];
  const int e  = blockIdx.z;
  const int d0 = blockIdx.x * 16, p0 = blockIdx.y * 16;
  const int tx = threadIdx.x, ty = threadIdx.y;
  ls[ty][tx] = W[((size_t)e * D + d0 + ty) * P + p0 + tx];
  __syncthreads();
  WT[((size_t)e * P + p0 + ty) * D + d0 + tx] = f2bf(ls[tx][ty]);
}

// ---------------- classifier v3: fp32 MLP -> idx[TOK]; writes x as bf16 -----
// TM=64 tok/block, 128 cols, BK=32. W1 via global_load_lds (double-buffered,
// zero reg cost). x via 2 float4 regs (fused f2bf->xb). 4tok x 8col/thread,
// split-column w-reads (c*4 and 64+c*4) -> 2-way banks. No VGPR cap.
__global__ __launch_bounds__(256) void classifier_kernel(
    const float* __restrict__ x,
    const float* __restrict__ W1, const float* __restrict__ b1,
    const float* __restrict__ g1, const float* __restrict__ be1,
    const float* __restrict__ m1, const float* __restrict__ v1,
    const float* __restrict__ W2, const float* __restrict__ b2,
    const float* __restrict__ g2, const float* __restrict__ be2,
    const float* __restrict__ m2, const float* __restrict__ v2,
    const float* __restrict__ W3, const float* __restrict__ b3,
    unsigned short* __restrict__ xb, int* __restrict__ idx_out)
{
  constexpr int TM = 64, BK = 32;
  // pass1: xs[2][32][68] @0 (17408 B) + ws[2][32][128] @17408 (32768 B) = 50176 B
  // pass2: h1s[128][68] @0 (34816 B) + h2s[32][68] @34816 (8704 B) = 43520 B
  __shared__ __align__(16) char smem[50176];
  float (*xs)[32][68]  = (float(*)[32][68])smem;
  float (*ws)[32][128] = (float(*)[32][128])(smem + 17408);
  float (*h1s)[68]     = (float(*)[68])smem;
  float (*h2s)[68]     = (float(*)[68])(smem + 34816);

  const int tid  = threadIdx.x;
  const int wave = tid >> 6;
  const int lane = tid & 63;
  const int t0   = blockIdx.x * TM;

  // x staging: row xr=tid>>2 (0..63), two float4 chunks at xc, xc+16
  const int xr = tid >> 2;
  const int xc = (tid & 3) * 4;

  // compute map: tokens tg*4..+3, cols cc*4..+3 and 64+cc*4..+3
  const int tg = tid >> 4;
  const int cc = tid & 15;

  float acc[4][8];
  #pragma unroll
  for (int i = 0; i < 4; ++i)
    #pragma unroll
    for (int j = 0; j < 8; ++j) acc[i][j] = 0.f;

  float4 px0, px1;

  auto issue_x = [&](int kt) {
    const float* base = &x[(size_t)(t0 + xr) * D + kt * BK + xc];
    px0 = *reinterpret_cast<const float4*>(base);
    px1 = *reinterpret_cast<const float4*>(base + 16);
  };
  auto commit_x = [&](int b, int kt) {
    xs[b][xc + 0][xr] = px0.x;  xs[b][xc + 1][xr] = px0.y;
    xs[b][xc + 2][xr] = px0.z;  xs[b][xc + 3][xr] = px0.w;
    xs[b][xc + 16][xr] = px1.x; xs[b][xc + 17][xr] = px1.y;
    xs[b][xc + 18][xr] = px1.z; xs[b][xc + 19][xr] = px1.w;
    ushort4 u0, u1;
    u0.x = f2bf(px0.x); u0.y = f2bf(px0.y); u0.z = f2bf(px0.z); u0.w = f2bf(px0.w);
    u1.x = f2bf(px1.x); u1.y = f2bf(px1.y); u1.z = f2bf(px1.z); u1.w = f2bf(px1.w);
    unsigned short* xbase = &xb[(size_t)(t0 + xr) * D + kt * BK + xc];
    *reinterpret_cast<ushort4*>(xbase)      = u0;
    *reinterpret_cast<ushort4*>(xbase + 16) = u1;
  };
  auto issue_w = [&](int b, int kt) {
    // 16 wave-ops total: op handles rows op*2+(lane>>5), chunk lane&31 (linear)
    char* ldsbase = (char*)&ws[b][0][0];
    const int kk = (lane >> 5);
    const int ch = (lane & 31) * 4;
    #pragma unroll
    for (int i = 0; i < 4; ++i) {
      const int op = wave * 4 + i;
      g2lds16(&W1[(size_t)(kt * BK + op * 2 + kk) * 128 + ch],
              (char*)ldsbase + op * 1024);
    }
  };

  issue_w(0, 0);
  issue_x(0);
  commit_x(0, 0);
  __syncthreads();   // drains g2lds (vmcnt 0) -> ws[0], xs[0] ready

  int buf = 0;
  for (int kt = 0; kt < D / BK; ++kt) {
    const int nb = buf ^ 1;
    if (kt < D / BK - 1) {
      issue_w(nb, kt + 1);   // async, in flight across compute
      issue_x(kt + 1);
    }
    #pragma unroll
    for (int kk = 0; kk < BK; ++kk) {
      const float4 xv = *reinterpret_cast<const float4*>(&xs[buf][kk][tg * 4]);
      const float4 wa = *reinterpret_cast<const float4*>(&ws[buf][kk][cc * 4]);
      const float4 wb = *reinterpret_cast<const float4*>(&ws[buf][kk][64 + cc * 4]);
      const float xr4[4] = {xv.x, xv.y, xv.z, xv.w};
      const float wr[8]  = {wa.x, wa.y, wa.z, wa.w, wb.x, wb.y, wb.z, wb.w};
      #pragma unroll
      for (int i = 0; i < 4; ++i)
        #pragma unroll
        for (int j = 0; j < 8; ++j)
          acc[i][j] = fmaf(xr4[i], wr[j], acc[i][j]);
    }
    if (kt < D / BK - 1) commit_x(nb, kt + 1);
    __syncthreads();
    buf = nb;
  }

  // BN1 + ReLU -> h1s[col][tok]  (xs/ws dead after final barrier)
  #pragma unroll
  for (int j = 0; j < 8; ++j) {
    const int col = (j < 4) ? (cc * 4 + j) : (60 + cc * 4 + j);
    const float A  = g1[col] / sqrtf(v1[col] + EPS);
    const float Bc = (b1[col] - m1[col]) * A + be1[col];
    float4 hv;
    hv.x = fmaxf(0.f, fmaf(acc[0][j], A, Bc));
    hv.y = fmaxf(0.f, fmaf(acc[1][j], A, Bc));
    hv.z = fmaxf(0.f, fmaf(acc[2][j], A, Bc));
    hv.w = fmaxf(0.f, fmaf(acc[3][j], A, Bc));
    *reinterpret_cast<float4*>(&h1s[col][tg * 4]) = hv;
  }
  __syncthreads();

  // layer 2: per thread 2 tokens x 4 cols
  {
    const int c2 = (tid & 7) * 4;
    const int t2 = (tid >> 3) * 2;
    f32x2 a2[4];
    #pragma unroll
    for (int c = 0; c < 4; ++c) a2[c] = (f32x2)0.f;
    #pragma unroll 8
    for (int j = 0; j < 128; ++j) {
      const f32x2 h = *reinterpret_cast<const f32x2*>(&h1s[j][t2]);
      const float4 w = *reinterpret_cast<const float4*>(&W2[j * 32 + c2]);
      const float wr[4] = {w.x, w.y, w.z, w.w};
      #pragma unroll
      for (int c = 0; c < 4; ++c) {
        a2[c][0] = fmaf(h[0], wr[c], a2[c][0]);
        a2[c][1] = fmaf(h[1], wr[c], a2[c][1]);
      }
    }
    #pragma unroll
    for (int c = 0; c < 4; ++c) {
      const int col = c2 + c;
      const float A  = g2[col] / sqrtf(v2[col] + EPS);
      const float Bc = (b2[col] - m2[col]) * A + be2[col];
      f32x2 hv;
      hv[0] = fmaxf(0.f, fmaf(a2[c][0], A, Bc));
      hv[1] = fmaxf(0.f, fmaf(a2[c][1], A, Bc));
      *reinterpret_cast<f32x2*>(&h2s[col][t2]) = hv;
    }
  }
  __syncthreads();

  // layer 3 + decision: idx = (logit > 0)  [== clip(round(sigmoid),0,1)]
  if (tid < TM) {
    float logit = b3[0];
    #pragma unroll
    for (int k = 0; k < 32; ++k)
      logit = fmaf(h2s[k][tid], W3[k], logit);
    idx_out[t0 + tid] = (logit > 0.f) ? 1 : 0;
  }
}

// ---------------- expert GEMM: bf16 MFMA, both experts, per-row select ------
__global__ __launch_bounds__(256) void expert_gemm_kernel(
    const unsigned short* __restrict__ xb,   // [TOK][D] bf16 bits
    const unsigned short* __restrict__ WT,   // [2][P][D] bf16 bits
    const float* __restrict__ b_exp,         // [2][P]
    const int* __restrict__ idx,             // [TOK]
    float* __restrict__ out)                 // [TOK][P]
{
  constexpr int GM = 128, GN = 80, GK = 32;
  __shared__ __align__(16) unsigned short As[GM * GK];      // 8 KB, 64 B rows
  __shared__ __align__(16) unsigned short Bs[2 * GN * GK];  // 10 KB

  const int tid  = threadIdx.x;
  const int wave = tid >> 6;
  const int lane = tid & 63;
  const int t0 = blockIdx.x * GM;
  const int p0 = blockIdx.y * GN;

  f32x4 acc[2][2][5];
  #pragma unroll
  for (int e = 0; e < 2; ++e)
    #pragma unroll
    for (int mf = 0; mf < 2; ++mf)
      #pragma unroll
      for (int nf = 0; nf < 5; ++nf) acc[e][mf][nf] = (f32x4)(0.f);

  // staging geometry: one wave-op = 1024 B = 16 rows of 64 B
  const int srow = lane >> 2;                       // row within 16-row chunk
  const int sswz = (lane & 3) ^ ((srow >> 1) & 3);  // source chunk (XOR swizzle)

  for (int kt = 0; kt < D / GK; ++kt) {
    const int k0 = kt * GK;
    #pragma unroll
    for (int i = 0; i < 5; ++i) {
      const int c = wave + i * 4;
      if (c < 18) {
        if (c < 8) {                                   // A: 8 chunks
          const int row = c * 16 + srow;
          g2lds16(xb + (size_t)(t0 + row) * D + k0 + sswz * 8,
                  (char*)As + c * 1024);
        } else {                                       // B: 2 experts x 5 chunks
          const int cb = c - 8;
          const int e  = (cb >= 5) ? 1 : 0;
          const int bc = cb - e * 5;
          const int pr = bc * 16 + srow;
          g2lds16(WT + ((size_t)e * P + p0 + pr) * D + k0 + sswz * 8,
                  (char*)Bs + e * 5120 + bc * 1024);
        }
      }
    }
    __syncthreads();

    bf16x8 af[2];
    #pragma unroll
    for (int mf = 0; mf < 2; ++mf) {
      const int r  = wave * 32 + mf * 16 + (lane & 15);
      const int ch = (lane >> 4) ^ ((r >> 1) & 3);
      af[mf] = *(const bf16x8*)((const char*)As + r * 64 + ch * 16);
    }
    #pragma unroll
    for (int e = 0; e < 2; ++e) {
      #pragma unroll
      for (int nf = 0; nf < 5; ++nf) {
        const int pr = nf * 16 + (lane & 15);
        const int ch = (lane >> 4) ^ ((pr >> 1) & 3);
        bf16x8 bfrag = *(const bf16x8*)((const char*)Bs + e * 5120 + pr * 64 + ch * 16);
        #pragma unroll
        for (int mf = 0; mf < 2; ++mf)
          acc[e][mf][nf] = __builtin_amdgcn_mfma_f32_16x16x32_bf16(
              af[mf], bfrag, acc[e][mf][nf], 0, 0, 0);
      }
    }
    __syncthreads();
  }

  // epilogue: per-row expert select + bias, store fp32
  const int col = lane & 15;
  const int rg  = lane >> 4;
  int er[2][4];
  #pragma unroll
  for (int mf = 0; mf < 2; ++mf)
    #pragma unroll
    for (int j = 0; j < 4; ++j)
      er[mf][j] = idx[t0 + wave * 32 + mf * 16 + rg * 4 + j];

  #pragma unroll
  for (int nf = 0; nf < 5; ++nf) {
    const int p = p0 + nf * 16 + col;
    const float be0 = b_exp[p];
    const float be1v = b_exp[P + p];
    #pragma unroll
    for (int mf = 0; mf < 2; ++mf) {
      #pragma unroll
      for (int j = 0; j < 4; ++j) {
        const int row = wave * 32 + mf * 16 + rg * 4 + j;
        const float v = er[mf][j] ? (acc[1][mf][nf][j] + be1v)
                                  : (acc[0][mf][nf][j] + be0);
        out[(size_t)(t0 + row) * P + p] = v;
      }
    }
  }
}

extern "C" void kernel_launch(void* const* d_in, const int* in_sizes, int n_in,
                              void* d_out, int out_size, void* d_ws, size_t ws_size,
                              hipStream_t stream) {
  const float* x     = (const float*)d_in[0];
  const float* W_exp = (const float*)d_in[1];
  const float* b_exp = (const float*)d_in[2];
  const float* W1 = (const float*)d_in[3];
  const float* b1 = (const float*)d_in[4];
  const float* g1 = (const float*)d_in[5];
  const float* be1 = (const float*)d_in[6];
  const float* m1 = (const float*)d_in[7];
  const float* v1 = (const float*)d_in[8];
  const float* W2 = (const float*)d_in[9];
  const float* b2 = (const float*)d_in[10];
  const float* g2 = (const float*)d_in[11];
  const float* be2 = (const float*)d_in[12];
  const float* m2 = (const float*)d_in[13];
  const float* v2 = (const float*)d_in[14];
  const float* W3 = (const float*)d_in[15];
  const float* b3 = (const float*)d_in[16];
  float* out = (float*)d_out;

  unsigned short* xb = (unsigned short*)d_ws;                       // 32 MB
  unsigned short* WT = (unsigned short*)((char*)d_ws + (size_t)TOK * D * 2);
  int* idx = (int*)((char*)d_ws + (size_t)TOK * D * 2 + (size_t)2 * P * D * 2);

  hipLaunchKernelGGL(wconv_kernel, dim3(D / 16, P / 16, 2), dim3(16, 16),
                     0, stream, W_exp, WT);
  hipLaunchKernelGGL(classifier_kernel, dim3(TOK / 64), dim3(256), 0, stream,
                     x, W1, b1, g1, be1, m1, v1, W2, b2, g2, be2, m2, v2, W3, b3,
                     xb, idx);
  hipLaunchKernelGGL(expert_gemm_kernel, dim3(TOK / 128, P / 80), dim3(256),
                     0, stream, xb, WT, b_exp, idx, out);
}

// Round 4
// 159.341 us; speedup vs baseline: 4.8290x; 1.3155x over previous
//
#include <hip/hip_runtime.h>

#define DEV __device__ __forceinline__

typedef __bf16 bf16x8 __attribute__((ext_vector_type(8)));
typedef float f32x4 __attribute__((ext_vector_type(4)));
typedef float f32x2 __attribute__((ext_vector_type(2)));

constexpr int TOK = 32768;   // B*N tokens
constexpr int D   = 512;
constexpr int P   = 720;
constexpr float EPS = 1e-5f;

DEV unsigned short f2bf(float f) {
  unsigned u = __float_as_uint(f);
  u += 0x7FFFu + ((u >> 16) & 1u);   // RNE (normals; inputs are finite randoms)
  return (unsigned short)(u >> 16);
}

DEV void g2lds16(const void* g, void* l) {
  __builtin_amdgcn_global_load_lds(
      (__attribute__((address_space(1))) void*)g,
      (__attribute__((address_space(3))) void*)l, 16, 0, 0);
}

// ---------------- W_exp [2][D][P] fp32 -> WT [2][P][D] bf16 -----------------
__global__ void wconv_kernel(const float* __restrict__ W,
                             unsigned short* __restrict__ WT) {
  __shared__ float ls[16][17];
  const int e  = blockIdx.z;
  const int d0 = blockIdx.x * 16, p0 = blockIdx.y * 16;
  const int tx = threadIdx.x, ty = threadIdx.y;
  ls[ty][tx] = W[((size_t)e * D + d0 + ty) * P + p0 + tx];
  __syncthreads();
  WT[((size_t)e * P + p0 + ty) * D + d0 + tx] = f2bf(ls[tx][ty]);
}

// ---------------- classifier v4: fp32 MLP -> idx[TOK]; writes x as bf16 -----
// Same double-buffered structure as v3, but: unroll 4 (cap reg pipelining),
// launch_bounds(256,3) (VGPR<=168), f32x2 packed FMAs (invite v_pk_fma_f32).
__global__ __launch_bounds__(256, 3) void classifier_kernel(
    const float* __restrict__ x,
    const float* __restrict__ W1, const float* __restrict__ b1,
    const float* __restrict__ g1, const float* __restrict__ be1,
    const float* __restrict__ m1, const float* __restrict__ v1,
    const float* __restrict__ W2, const float* __restrict__ b2,
    const float* __restrict__ g2, const float* __restrict__ be2,
    const float* __restrict__ m2, const float* __restrict__ v2,
    const float* __restrict__ W3, const float* __restrict__ b3,
    unsigned short* __restrict__ xb, int* __restrict__ idx_out)
{
  constexpr int TM = 64, BK = 32;
  // pass1: xs[2][32][68] @0 (17408 B) + ws[2][32][128] @17408 (32768 B) = 50176 B
  // pass2: h1s[128][68] @0 (34816 B) + h2s[32][68] @34816 (8704 B) = 43520 B
  __shared__ __align__(16) char smem[50176];
  float (*xs)[32][68]  = (float(*)[32][68])smem;
  float (*ws)[32][128] = (float(*)[32][128])(smem + 17408);
  float (*h1s)[68]     = (float(*)[68])smem;
  float (*h2s)[68]     = (float(*)[68])(smem + 34816);

  const int tid  = threadIdx.x;
  const int wave = tid >> 6;
  const int lane = tid & 63;
  const int t0   = blockIdx.x * TM;

  // x staging: row xr=tid>>2 (0..63), two float4 chunks at xc, xc+16
  const int xr = tid >> 2;
  const int xc = (tid & 3) * 4;

  // compute map: tokens tg*4..+3, cols cc*4..+3 and 64+cc*4..+3
  const int tg = tid >> 4;
  const int cc = tid & 15;

  f32x2 acc[2][8];   // [token-pair][col j]; tokens tg*4+2p, tg*4+2p+1
  #pragma unroll
  for (int p = 0; p < 2; ++p)
    #pragma unroll
    for (int j = 0; j < 8; ++j) acc[p][j] = (f32x2)0.f;

  float4 px0, px1;

  auto issue_x = [&](int kt) {
    const float* base = &x[(size_t)(t0 + xr) * D + kt * BK + xc];
    px0 = *reinterpret_cast<const float4*>(base);
    px1 = *reinterpret_cast<const float4*>(base + 16);
  };
  auto commit_x = [&](int b, int kt) {
    xs[b][xc + 0][xr] = px0.x;  xs[b][xc + 1][xr] = px0.y;
    xs[b][xc + 2][xr] = px0.z;  xs[b][xc + 3][xr] = px0.w;
    xs[b][xc + 16][xr] = px1.x; xs[b][xc + 17][xr] = px1.y;
    xs[b][xc + 18][xr] = px1.z; xs[b][xc + 19][xr] = px1.w;
    ushort4 u0, u1;
    u0.x = f2bf(px0.x); u0.y = f2bf(px0.y); u0.z = f2bf(px0.z); u0.w = f2bf(px0.w);
    u1.x = f2bf(px1.x); u1.y = f2bf(px1.y); u1.z = f2bf(px1.z); u1.w = f2bf(px1.w);
    unsigned short* xbase = &xb[(size_t)(t0 + xr) * D + kt * BK + xc];
    *reinterpret_cast<ushort4*>(xbase)      = u0;
    *reinterpret_cast<ushort4*>(xbase + 16) = u1;
  };
  auto issue_w = [&](int b, int kt) {
    // 16 wave-ops: op covers rows op*2+(lane>>5), 16B chunk (lane&31) (linear)
    char* ldsbase = (char*)&ws[b][0][0];
    const int kk = (lane >> 5);
    const int ch = (lane & 31) * 4;
    #pragma unroll
    for (int i = 0; i < 4; ++i) {
      const int op = wave * 4 + i;
      g2lds16(&W1[(size_t)(kt * BK + op * 2 + kk) * 128 + ch],
              (char*)ldsbase + op * 1024);
    }
  };

  issue_w(0, 0);
  issue_x(0);
  commit_x(0, 0);
  __syncthreads();   // drains g2lds (vmcnt 0) -> ws[0], xs[0] ready

  int buf = 0;
  for (int kt = 0; kt < D / BK; ++kt) {
    const int nb = buf ^ 1;
    if (kt < D / BK - 1) {
      issue_w(nb, kt + 1);   // async, in flight across compute
      issue_x(kt + 1);
    }
    #pragma unroll 4
    for (int kk = 0; kk < BK; ++kk) {
      const f32x4 xv = *reinterpret_cast<const f32x4*>(&xs[buf][kk][tg * 4]);
      const f32x4 wa = *reinterpret_cast<const f32x4*>(&ws[buf][kk][cc * 4]);
      const f32x4 wb = *reinterpret_cast<const f32x4*>(&ws[buf][kk][64 + cc * 4]);
      f32x2 xp[2];
      xp[0][0] = xv[0]; xp[0][1] = xv[1];
      xp[1][0] = xv[2]; xp[1][1] = xv[3];
      const float wr[8] = {wa[0], wa[1], wa[2], wa[3], wb[0], wb[1], wb[2], wb[3]};
      #pragma unroll
      for (int p = 0; p < 2; ++p)
        #pragma unroll
        for (int j = 0; j < 8; ++j) {
          f32x2 wv = {wr[j], wr[j]};
          acc[p][j] = __builtin_elementwise_fma(xp[p], wv, acc[p][j]);
        }
    }
    if (kt < D / BK - 1) commit_x(nb, kt + 1);
    __syncthreads();
    buf = nb;
  }

  // BN1 + ReLU -> h1s[col][tok]  (xs/ws dead after final barrier)
  #pragma unroll
  for (int j = 0; j < 8; ++j) {
    const int col = (j < 4) ? (cc * 4 + j) : (60 + cc * 4 + j);
    const float A  = g1[col] / sqrtf(v1[col] + EPS);
    const float Bc = (b1[col] - m1[col]) * A + be1[col];
    float4 hv;
    hv.x = fmaxf(0.f, fmaf(acc[0][j][0], A, Bc));
    hv.y = fmaxf(0.f, fmaf(acc[0][j][1], A, Bc));
    hv.z = fmaxf(0.f, fmaf(acc[1][j][0], A, Bc));
    hv.w = fmaxf(0.f, fmaf(acc[1][j][1], A, Bc));
    *reinterpret_cast<float4*>(&h1s[col][tg * 4]) = hv;
  }
  __syncthreads();

  // layer 2: per thread 2 tokens x 4 cols
  {
    const int c2 = (tid & 7) * 4;
    const int t2 = (tid >> 3) * 2;
    f32x2 a2[4];
    #pragma unroll
    for (int c = 0; c < 4; ++c) a2[c] = (f32x2)0.f;
    #pragma unroll 8
    for (int j = 0; j < 128; ++j) {
      const f32x2 h = *reinterpret_cast<const f32x2*>(&h1s[j][t2]);
      const float4 w = *reinterpret_cast<const float4*>(&W2[j * 32 + c2]);
      const float wr[4] = {w.x, w.y, w.z, w.w};
      #pragma unroll
      for (int c = 0; c < 4; ++c) {
        f32x2 wv = {wr[c], wr[c]};
        a2[c] = __builtin_elementwise_fma(h, wv, a2[c]);
      }
    }
    #pragma unroll
    for (int c = 0; c < 4; ++c) {
      const int col = c2 + c;
      const float A  = g2[col] / sqrtf(v2[col] + EPS);
      const float Bc = (b2[col] - m2[col]) * A + be2[col];
      f32x2 hv;
      hv[0] = fmaxf(0.f, fmaf(a2[c][0], A, Bc));
      hv[1] = fmaxf(0.f, fmaf(a2[c][1], A, Bc));
      *reinterpret_cast<f32x2*>(&h2s[col][t2]) = hv;
    }
  }
  __syncthreads();

  // layer 3 + decision: idx = (logit > 0)  [== clip(round(sigmoid),0,1)]
  if (tid < TM) {
    float logit = b3[0];
    #pragma unroll
    for (int k = 0; k < 32; ++k)
      logit = fmaf(h2s[k][tid], W3[k], logit);
    idx_out[t0 + tid] = (logit > 0.f) ? 1 : 0;
  }
}

// ---------------- expert GEMM: bf16 MFMA, both experts, per-row select ------
__global__ __launch_bounds__(256) void expert_gemm_kernel(
    const unsigned short* __restrict__ xb,   // [TOK][D] bf16 bits
    const unsigned short* __restrict__ WT,   // [2][P][D] bf16 bits
    const float* __restrict__ b_exp,         // [2][P]
    const int* __restrict__ idx,             // [TOK]
    float* __restrict__ out)                 // [TOK][P]
{
  constexpr int GM = 128, GN = 80, GK = 32;
  __shared__ __align__(16) unsigned short As[GM * GK];      // 8 KB, 64 B rows
  __shared__ __align__(16) unsigned short Bs[2 * GN * GK];  // 10 KB

  const int tid  = threadIdx.x;
  const int wave = tid >> 6;
  const int lane = tid & 63;
  const int t0 = blockIdx.x * GM;
  const int p0 = blockIdx.y * GN;

  f32x4 acc[2][2][5];
  #pragma unroll
  for (int e = 0; e < 2; ++e)
    #pragma unroll
    for (int mf = 0; mf < 2; ++mf)
      #pragma unroll
      for (int nf = 0; nf < 5; ++nf) acc[e][mf][nf] = (f32x4)(0.f);

  // staging geometry: one wave-op = 1024 B = 16 rows of 64 B
  const int srow = lane >> 2;                       // row within 16-row chunk
  const int sswz = (lane & 3) ^ ((srow >> 1) & 3);  // source chunk (XOR swizzle)

  for (int kt = 0; kt < D / GK; ++kt) {
    const int k0 = kt * GK;
    #pragma unroll
    for (int i = 0; i < 5; ++i) {
      const int c = wave + i * 4;
      if (c < 18) {
        if (c < 8) {                                   // A: 8 chunks
          const int row = c * 16 + srow;
          g2lds16(xb + (size_t)(t0 + row) * D + k0 + sswz * 8,
                  (char*)As + c * 1024);
        } else {                                       // B: 2 experts x 5 chunks
          const int cb = c - 8;
          const int e  = (cb >= 5) ? 1 : 0;
          const int bc = cb - e * 5;
          const int pr = bc * 16 + srow;
          g2lds16(WT + ((size_t)e * P + p0 + pr) * D + k0 + sswz * 8,
                  (char*)Bs + e * 5120 + bc * 1024);
        }
      }
    }
    __syncthreads();

    bf16x8 af[2];
    #pragma unroll
    for (int mf = 0; mf < 2; ++mf) {
      const int r  = wave * 32 + mf * 16 + (lane & 15);
      const int ch = (lane >> 4) ^ ((r >> 1) & 3);
      af[mf] = *(const bf16x8*)((const char*)As + r * 64 + ch * 16);
    }
    #pragma unroll
    for (int e = 0; e < 2; ++e) {
      #pragma unroll
      for (int nf = 0; nf < 5; ++nf) {
        const int pr = nf * 16 + (lane & 15);
        const int ch = (lane >> 4) ^ ((pr >> 1) & 3);
        bf16x8 bfrag = *(const bf16x8*)((const char*)Bs + e * 5120 + pr * 64 + ch * 16);
        #pragma unroll
        for (int mf = 0; mf < 2; ++mf)
          acc[e][mf][nf] = __builtin_amdgcn_mfma_f32_16x16x32_bf16(
              af[mf], bfrag, acc[e][mf][nf], 0, 0, 0);
      }
    }
    __syncthreads();
  }

  // epilogue: per-row expert select + bias, store fp32
  const int col = lane & 15;
  const int rg  = lane >> 4;
  int er[2][4];
  #pragma unroll
  for (int mf = 0; mf < 2; ++mf)
    #pragma unroll
    for (int j = 0; j < 4; ++j)
      er[mf][j] = idx[t0 + wave * 32 + mf * 16 + rg * 4 + j];

  #pragma unroll
  for (int nf = 0; nf < 5; ++nf) {
    const int p = p0 + nf * 16 + col;
    const float be0 = b_exp[p];
    const float be1v = b_exp[P + p];
    #pragma unroll
    for (int mf = 0; mf < 2; ++mf) {
      #pragma unroll
      for (int j = 0; j < 4; ++j) {
        const int row = wave * 32 + mf * 16 + rg * 4 + j;
        const float v = er[mf][j] ? (acc[1][mf][nf][j] + be1v)
                                  : (acc[0][mf][nf][j] + be0);
        out[(size_t)(t0 + row) * P + p] = v;
      }
    }
  }
}

extern "C" void kernel_launch(void* const* d_in, const int* in_sizes, int n_in,
                              void* d_out, int out_size, void* d_ws, size_t ws_size,
                              hipStream_t stream) {
  const float* x     = (const float*)d_in[0];
  const float* W_exp = (const float*)d_in[1];
  const float* b_exp = (const float*)d_in[2];
  const float* W1 = (const float*)d_in[3];
  const float* b1 = (const float*)d_in[4];
  const float* g1 = (const float*)d_in[5];
  const float* be1 = (const float*)d_in[6];
  const float* m1 = (const float*)d_in[7];
  const float* v1 = (const float*)d_in[8];
  const float* W2 = (const float*)d_in[9];
  const float* b2 = (const float*)d_in[10];
  const float* g2 = (const float*)d_in[11];
  const float* be2 = (const float*)d_in[12];
  const float* m2 = (const float*)d_in[13];
  const float* v2 = (const float*)d_in[14];
  const float* W3 = (const float*)d_in[15];
  const float* b3 = (const float*)d_in[16];
  float* out = (float*)d_out;

  unsigned short* xb = (unsigned short*)d_ws;                       // 32 MB
  unsigned short* WT = (unsigned short*)((char*)d_ws + (size_t)TOK * D * 2);
  int* idx = (int*)((char*)d_ws + (size_t)TOK * D * 2 + (size_t)2 * P * D * 2);

  hipLaunchKernelGGL(wconv_kernel, dim3(D / 16, P / 16, 2), dim3(16, 16),
                     0, stream, W_exp, WT);
  hipLaunchKernelGGL(classifier_kernel, dim3(TOK / 64), dim3(256), 0, stream,
                     x, W1, b1, g1, be1, m1, v1, W2, b2, g2, be2, m2, v2, W3, b3,
                     xb, idx);
  hipLaunchKernelGGL(expert_gemm_kernel, dim3(TOK / 128, P / 80), dim3(256),
                     0, stream, xb, WT, b_exp, idx, out);
}

// Round 5
// 155.000 us; speedup vs baseline: 4.9642x; 1.0280x over previous
//
#include <hip/hip_runtime.h>

#define DEV __device__ __forceinline__

typedef __bf16 bf16x8 __attribute__((ext_vector_type(8)));
typedef float f32x4 __attribute__((ext_vector_type(4)));
typedef float f32x2 __attribute__((ext_vector_type(2)));

constexpr int TOK = 32768;   // B*N tokens
constexpr int D   = 512;
constexpr int P   = 720;
constexpr float EPS = 1e-5f;

DEV unsigned short f2bf(float f) {
  unsigned u = __float_as_uint(f);
  u += 0x7FFFu + ((u >> 16) & 1u);   // RNE (normals; inputs are finite randoms)
  return (unsigned short)(u >> 16);
}

DEV void g2lds16(const void* g, void* l) {
  __builtin_amdgcn_global_load_lds(
      (__attribute__((address_space(1))) void*)g,
      (__attribute__((address_space(3))) void*)l, 16, 0, 0);
}

// ---------------- W_exp [2][D][P] fp32 -> WT [2][P][D] bf16 -----------------
__global__ void wconv_kernel(const float* __restrict__ W,
                             unsigned short* __restrict__ WT) {
  __shared__ float ls[16][17];
  const int e  = blockIdx.z;
  const int d0 = blockIdx.x * 16, p0 = blockIdx.y * 16;
  const int tx = threadIdx.x, ty = threadIdx.y;
  ls[ty][tx] = W[((size_t)e * D + d0 + ty) * P + p0 + tx];
  __syncthreads();
  WT[((size_t)e * P + p0 + ty) * D + d0 + tx] = f2bf(ls[tx][ty]);
}

// ---------------- classifier v4: fp32 MLP -> idx[TOK]; writes x as bf16 -----
__global__ __launch_bounds__(256, 3) void classifier_kernel(
    const float* __restrict__ x,
    const float* __restrict__ W1, const float* __restrict__ b1,
    const float* __restrict__ g1, const float* __restrict__ be1,
    const float* __restrict__ m1, const float* __restrict__ v1,
    const float* __restrict__ W2, const float* __restrict__ b2,
    const float* __restrict__ g2, const float* __restrict__ be2,
    const float* __restrict__ m2, const float* __restrict__ v2,
    const float* __restrict__ W3, const float* __restrict__ b3,
    unsigned short* __restrict__ xb, int* __restrict__ idx_out)
{
  constexpr int TM = 64, BK = 32;
  __shared__ __align__(16) char smem[50176];
  float (*xs)[32][68]  = (float(*)[32][68])smem;
  float (*ws)[32][128] = (float(*)[32][128])(smem + 17408);
  float (*h1s)[68]     = (float(*)[68])smem;
  float (*h2s)[68]     = (float(*)[68])(smem + 34816);

  const int tid  = threadIdx.x;
  const int wave = tid >> 6;
  const int lane = tid & 63;
  const int t0   = blockIdx.x * TM;

  const int xr = tid >> 2;
  const int xc = (tid & 3) * 4;
  const int tg = tid >> 4;
  const int cc = tid & 15;

  f32x2 acc[2][8];
  #pragma unroll
  for (int p = 0; p < 2; ++p)
    #pragma unroll
    for (int j = 0; j < 8; ++j) acc[p][j] = (f32x2)0.f;

  float4 px0, px1;

  auto issue_x = [&](int kt) {
    const float* base = &x[(size_t)(t0 + xr) * D + kt * BK + xc];
    px0 = *reinterpret_cast<const float4*>(base);
    px1 = *reinterpret_cast<const float4*>(base + 16);
  };
  auto commit_x = [&](int b, int kt) {
    xs[b][xc + 0][xr] = px0.x;  xs[b][xc + 1][xr] = px0.y;
    xs[b][xc + 2][xr] = px0.z;  xs[b][xc + 3][xr] = px0.w;
    xs[b][xc + 16][xr] = px1.x; xs[b][xc + 17][xr] = px1.y;
    xs[b][xc + 18][xr] = px1.z; xs[b][xc + 19][xr] = px1.w;
    ushort4 u0, u1;
    u0.x = f2bf(px0.x); u0.y = f2bf(px0.y); u0.z = f2bf(px0.z); u0.w = f2bf(px0.w);
    u1.x = f2bf(px1.x); u1.y = f2bf(px1.y); u1.z = f2bf(px1.z); u1.w = f2bf(px1.w);
    unsigned short* xbase = &xb[(size_t)(t0 + xr) * D + kt * BK + xc];
    *reinterpret_cast<ushort4*>(xbase)      = u0;
    *reinterpret_cast<ushort4*>(xbase + 16) = u1;
  };
  auto issue_w = [&](int b, int kt) {
    char* ldsbase = (char*)&ws[b][0][0];
    const int kk = (lane >> 5);
    const int ch = (lane & 31) * 4;
    #pragma unroll
    for (int i = 0; i < 4; ++i) {
      const int op = wave * 4 + i;
      g2lds16(&W1[(size_t)(kt * BK + op * 2 + kk) * 128 + ch],
              (char*)ldsbase + op * 1024);
    }
  };

  issue_w(0, 0);
  issue_x(0);
  commit_x(0, 0);
  __syncthreads();

  int buf = 0;
  for (int kt = 0; kt < D / BK; ++kt) {
    const int nb = buf ^ 1;
    if (kt < D / BK - 1) {
      issue_w(nb, kt + 1);
      issue_x(kt + 1);
    }
    #pragma unroll 4
    for (int kk = 0; kk < BK; ++kk) {
      const f32x4 xv = *reinterpret_cast<const f32x4*>(&xs[buf][kk][tg * 4]);
      const f32x4 wa = *reinterpret_cast<const f32x4*>(&ws[buf][kk][cc * 4]);
      const f32x4 wb = *reinterpret_cast<const f32x4*>(&ws[buf][kk][64 + cc * 4]);
      f32x2 xp[2];
      xp[0][0] = xv[0]; xp[0][1] = xv[1];
      xp[1][0] = xv[2]; xp[1][1] = xv[3];
      const float wr[8] = {wa[0], wa[1], wa[2], wa[3], wb[0], wb[1], wb[2], wb[3]};
      #pragma unroll
      for (int p = 0; p < 2; ++p)
        #pragma unroll
        for (int j = 0; j < 8; ++j) {
          f32x2 wv = {wr[j], wr[j]};
          acc[p][j] = __builtin_elementwise_fma(xp[p], wv, acc[p][j]);
        }
    }
    if (kt < D / BK - 1) commit_x(nb, kt + 1);
    __syncthreads();
    buf = nb;
  }

  #pragma unroll
  for (int j = 0; j < 8; ++j) {
    const int col = (j < 4) ? (cc * 4 + j) : (60 + cc * 4 + j);
    const float A  = g1[col] / sqrtf(v1[col] + EPS);
    const float Bc = (b1[col] - m1[col]) * A + be1[col];
    float4 hv;
    hv.x = fmaxf(0.f, fmaf(acc[0][j][0], A, Bc));
    hv.y = fmaxf(0.f, fmaf(acc[0][j][1], A, Bc));
    hv.z = fmaxf(0.f, fmaf(acc[1][j][0], A, Bc));
    hv.w = fmaxf(0.f, fmaf(acc[1][j][1], A, Bc));
    *reinterpret_cast<float4*>(&h1s[col][tg * 4]) = hv;
  }
  __syncthreads();

  {
    const int c2 = (tid & 7) * 4;
    const int t2 = (tid >> 3) * 2;
    f32x2 a2[4];
    #pragma unroll
    for (int c = 0; c < 4; ++c) a2[c] = (f32x2)0.f;
    #pragma unroll 8
    for (int j = 0; j < 128; ++j) {
      const f32x2 h = *reinterpret_cast<const f32x2*>(&h1s[j][t2]);
      const float4 w = *reinterpret_cast<const float4*>(&W2[j * 32 + c2]);
      const float wr[4] = {w.x, w.y, w.z, w.w};
      #pragma unroll
      for (int c = 0; c < 4; ++c) {
        f32x2 wv = {wr[c], wr[c]};
        a2[c] = __builtin_elementwise_fma(h, wv, a2[c]);
      }
    }
    #pragma unroll
    for (int c = 0; c < 4; ++c) {
      const int col = c2 + c;
      const float A  = g2[col] / sqrtf(v2[col] + EPS);
      const float Bc = (b2[col] - m2[col]) * A + be2[col];
      f32x2 hv;
      hv[0] = fmaxf(0.f, fmaf(a2[c][0], A, Bc));
      hv[1] = fmaxf(0.f, fmaf(a2[c][1], A, Bc));
      *reinterpret_cast<f32x2*>(&h2s[col][t2]) = hv;
    }
  }
  __syncthreads();

  if (tid < TM) {
    float logit = b3[0];
    #pragma unroll
    for (int k = 0; k < 32; ++k)
      logit = fmaf(h2s[k][tid], W3[k], logit);
    idx_out[t0 + tid] = (logit > 0.f) ? 1 : 0;
  }
}

// ---------------- expert GEMM v2: double-buffered async staging -------------
// T3-minimum 2-phase: STAGE(buf^1, kt+1) issued BEFORE compute of buf; one
// barrier per K-step drains the prefetch. Grid = (P-tiles, tok-tiles) so 9
// consecutive blocks share one A-tile in L2.
__global__ __launch_bounds__(256) void expert_gemm_kernel(
    const unsigned short* __restrict__ xb,   // [TOK][D] bf16 bits
    const unsigned short* __restrict__ WT,   // [2][P][D] bf16 bits
    const float* __restrict__ b_exp,         // [2][P]
    const int* __restrict__ idx,             // [TOK]
    float* __restrict__ out)                 // [TOK][P]
{
  constexpr int GM = 128, GN = 80, GK = 32;
  __shared__ __align__(16) unsigned short As[2][GM * GK];      // 2 x 8 KB
  __shared__ __align__(16) unsigned short Bs[2][2 * GN * GK];  // 2 x 10 KB

  const int tid  = threadIdx.x;
  const int wave = tid >> 6;
  const int lane = tid & 63;
  const int p0 = blockIdx.x * GN;
  const int t0 = blockIdx.y * GM;

  f32x4 acc[2][2][5];
  #pragma unroll
  for (int e = 0; e < 2; ++e)
    #pragma unroll
    for (int mf = 0; mf < 2; ++mf)
      #pragma unroll
      for (int nf = 0; nf < 5; ++nf) acc[e][mf][nf] = (f32x4)(0.f);

  // staging geometry: one wave-op = 1024 B = 16 rows of 64 B
  const int srow = lane >> 2;                       // row within 16-row chunk
  const int sswz = (lane & 3) ^ ((srow >> 1) & 3);  // source chunk (XOR swizzle)

  auto stage = [&](int b, int kt) {
    const int k0 = kt * GK;
    #pragma unroll
    for (int i = 0; i < 5; ++i) {
      const int c = wave + i * 4;
      if (c < 18) {
        if (c < 8) {                                   // A: 8 chunks
          const int row = c * 16 + srow;
          g2lds16(xb + (size_t)(t0 + row) * D + k0 + sswz * 8,
                  (char*)As[b] + c * 1024);
        } else {                                       // B: 2 experts x 5 chunks
          const int cb = c - 8;
          const int e  = (cb >= 5) ? 1 : 0;
          const int bc = cb - e * 5;
          const int pr = bc * 16 + srow;
          g2lds16(WT + ((size_t)e * P + p0 + pr) * D + k0 + sswz * 8,
                  (char*)Bs[b] + e * 5120 + bc * 1024);
        }
      }
    }
  };

  stage(0, 0);
  __syncthreads();   // drain -> buffer 0 ready

  int buf = 0;
  constexpr int NT = D / GK;
  for (int kt = 0; kt < NT; ++kt) {
    if (kt + 1 < NT) stage(buf ^ 1, kt + 1);   // in flight across compute

    bf16x8 af[2];
    #pragma unroll
    for (int mf = 0; mf < 2; ++mf) {
      const int r  = wave * 32 + mf * 16 + (lane & 15);
      const int ch = (lane >> 4) ^ ((r >> 1) & 3);
      af[mf] = *(const bf16x8*)((const char*)As[buf] + r * 64 + ch * 16);
    }
    #pragma unroll
    for (int e = 0; e < 2; ++e) {
      #pragma unroll
      for (int nf = 0; nf < 5; ++nf) {
        const int pr = nf * 16 + (lane & 15);
        const int ch = (lane >> 4) ^ ((pr >> 1) & 3);
        bf16x8 bfrag = *(const bf16x8*)((const char*)Bs[buf] + e * 5120 + pr * 64 + ch * 16);
        #pragma unroll
        for (int mf = 0; mf < 2; ++mf)
          acc[e][mf][nf] = __builtin_amdgcn_mfma_f32_16x16x32_bf16(
              af[mf], bfrag, acc[e][mf][nf], 0, 0, 0);
      }
    }
    __syncthreads();   // drains prefetch (vmcnt 0) + protects LDS reuse
    buf ^= 1;
  }

  // epilogue: per-row expert select + bias, store fp32
  const int col = lane & 15;
  const int rg  = lane >> 4;
  int er[2][4];
  #pragma unroll
  for (int mf = 0; mf < 2; ++mf)
    #pragma unroll
    for (int j = 0; j < 4; ++j)
      er[mf][j] = idx[t0 + wave * 32 + mf * 16 + rg * 4 + j];

  #pragma unroll
  for (int nf = 0; nf < 5; ++nf) {
    const int p = p0 + nf * 16 + col;
    const float be0 = b_exp[p];
    const float be1v = b_exp[P + p];
    #pragma unroll
    for (int mf = 0; mf < 2; ++mf) {
      #pragma unroll
      for (int j = 0; j < 4; ++j) {
        const int row = wave * 32 + mf * 16 + rg * 4 + j;
        const float v = er[mf][j] ? (acc[1][mf][nf][j] + be1v)
                                  : (acc[0][mf][nf][j] + be0);
        out[(size_t)(t0 + row) * P + p] = v;
      }
    }
  }
}

extern "C" void kernel_launch(void* const* d_in, const int* in_sizes, int n_in,
                              void* d_out, int out_size, void* d_ws, size_t ws_size,
                              hipStream_t stream) {
  const float* x     = (const float*)d_in[0];
  const float* W_exp = (const float*)d_in[1];
  const float* b_exp = (const float*)d_in[2];
  const float* W1 = (const float*)d_in[3];
  const float* b1 = (const float*)d_in[4];
  const float* g1 = (const float*)d_in[5];
  const float* be1 = (const float*)d_in[6];
  const float* m1 = (const float*)d_in[7];
  const float* v1 = (const float*)d_in[8];
  const float* W2 = (const float*)d_in[9];
  const float* b2 = (const float*)d_in[10];
  const float* g2 = (const float*)d_in[11];
  const float* be2 = (const float*)d_in[12];
  const float* m2 = (const float*)d_in[13];
  const float* v2 = (const float*)d_in[14];
  const float* W3 = (const float*)d_in[15];
  const float* b3 = (const float*)d_in[16];
  float* out = (float*)d_out;

  unsigned short* xb = (unsigned short*)d_ws;                       // 32 MB
  unsigned short* WT = (unsigned short*)((char*)d_ws + (size_t)TOK * D * 2);
  int* idx = (int*)((char*)d_ws + (size_t)TOK * D * 2 + (size_t)2 * P * D * 2);

  hipLaunchKernelGGL(wconv_kernel, dim3(D / 16, P / 16, 2), dim3(16, 16),
                     0, stream, W_exp, WT);
  hipLaunchKernelGGL(classifier_kernel, dim3(TOK / 64), dim3(256), 0, stream,
                     x, W1, b1, g1, be1, m1, v1, W2, b2, g2, be2, m2, v2, W3, b3,
                     xb, idx);
  hipLaunchKernelGGL(expert_gemm_kernel, dim3(P / 80, TOK / 128), dim3(256),
                     0, stream, xb, WT, b_exp, idx, out);
}

// Round 6
// 141.785 us; speedup vs baseline: 5.4269x; 1.0932x over previous
//
#include <hip/hip_runtime.h>

#define DEV __device__ __forceinline__

typedef __bf16 bf16x8 __attribute__((ext_vector_type(8)));
typedef float f32x4 __attribute__((ext_vector_type(4)));
typedef float f32x2 __attribute__((ext_vector_type(2)));

constexpr int TOK = 32768;   // B*N tokens
constexpr int D   = 512;
constexpr int P   = 720;
constexpr float EPS = 1e-5f;

DEV unsigned short f2bf(float f) {
  unsigned u = __float_as_uint(f);
  u += 0x7FFFu + ((u >> 16) & 1u);   // RNE (normals; inputs are finite randoms)
  return (unsigned short)(u >> 16);
}

DEV void g2lds16(const void* g, void* l) {
  __builtin_amdgcn_global_load_lds(
      (__attribute__((address_space(1))) void*)g,
      (__attribute__((address_space(3))) void*)l, 16, 0, 0);
}

// ---------------- W_exp [2][D][P] fp32 -> WT [2][P][D] bf16 -----------------
__global__ void wconv_kernel(const float* __restrict__ W,
                             unsigned short* __restrict__ WT) {
  __shared__ float ls[16][17];
  const int e  = blockIdx.z;
  const int d0 = blockIdx.x * 16, p0 = blockIdx.y * 16;
  const int tx = threadIdx.x, ty = threadIdx.y;
  ls[ty][tx] = W[((size_t)e * D + d0 + ty) * P + p0 + tx];
  __syncthreads();
  WT[((size_t)e * P + p0 + ty) * D + d0 + tx] = f2bf(ls[tx][ty]);
}

// ---------------- classifier v4: fp32 MLP -> idx[TOK]; writes x as bf16 -----
__global__ __launch_bounds__(256, 3) void classifier_kernel(
    const float* __restrict__ x,
    const float* __restrict__ W1, const float* __restrict__ b1,
    const float* __restrict__ g1, const float* __restrict__ be1,
    const float* __restrict__ m1, const float* __restrict__ v1,
    const float* __restrict__ W2, const float* __restrict__ b2,
    const float* __restrict__ g2, const float* __restrict__ be2,
    const float* __restrict__ m2, const float* __restrict__ v2,
    const float* __restrict__ W3, const float* __restrict__ b3,
    unsigned short* __restrict__ xb, int* __restrict__ idx_out)
{
  constexpr int TM = 64, BK = 32;
  __shared__ __align__(16) char smem[50176];
  float (*xs)[32][68]  = (float(*)[32][68])smem;
  float (*ws)[32][128] = (float(*)[32][128])(smem + 17408);
  float (*h1s)[68]     = (float(*)[68])smem;
  float (*h2s)[68]     = (float(*)[68])(smem + 34816);

  const int tid  = threadIdx.x;
  const int wave = tid >> 6;
  const int lane = tid & 63;
  const int t0   = blockIdx.x * TM;

  const int xr = tid >> 2;
  const int xc = (tid & 3) * 4;
  const int tg = tid >> 4;
  const int cc = tid & 15;

  f32x2 acc[2][8];
  #pragma unroll
  for (int p = 0; p < 2; ++p)
    #pragma unroll
    for (int j = 0; j < 8; ++j) acc[p][j] = (f32x2)0.f;

  float4 px0, px1;

  auto issue_x = [&](int kt) {
    const float* base = &x[(size_t)(t0 + xr) * D + kt * BK + xc];
    px0 = *reinterpret_cast<const float4*>(base);
    px1 = *reinterpret_cast<const float4*>(base + 16);
  };
  auto commit_x = [&](int b, int kt) {
    xs[b][xc + 0][xr] = px0.x;  xs[b][xc + 1][xr] = px0.y;
    xs[b][xc + 2][xr] = px0.z;  xs[b][xc + 3][xr] = px0.w;
    xs[b][xc + 16][xr] = px1.x; xs[b][xc + 17][xr] = px1.y;
    xs[b][xc + 18][xr] = px1.z; xs[b][xc + 19][xr] = px1.w;
    ushort4 u0, u1;
    u0.x = f2bf(px0.x); u0.y = f2bf(px0.y); u0.z = f2bf(px0.z); u0.w = f2bf(px0.w);
    u1.x = f2bf(px1.x); u1.y = f2bf(px1.y); u1.z = f2bf(px1.z); u1.w = f2bf(px1.w);
    unsigned short* xbase = &xb[(size_t)(t0 + xr) * D + kt * BK + xc];
    *reinterpret_cast<ushort4*>(xbase)      = u0;
    *reinterpret_cast<ushort4*>(xbase + 16) = u1;
  };
  auto issue_w = [&](int b, int kt) {
    char* ldsbase = (char*)&ws[b][0][0];
    const int kk = (lane >> 5);
    const int ch = (lane & 31) * 4;
    #pragma unroll
    for (int i = 0; i < 4; ++i) {
      const int op = wave * 4 + i;
      g2lds16(&W1[(size_t)(kt * BK + op * 2 + kk) * 128 + ch],
              (char*)ldsbase + op * 1024);
    }
  };

  issue_w(0, 0);
  issue_x(0);
  commit_x(0, 0);
  __syncthreads();

  int buf = 0;
  for (int kt = 0; kt < D / BK; ++kt) {
    const int nb = buf ^ 1;
    if (kt < D / BK - 1) {
      issue_w(nb, kt + 1);
      issue_x(kt + 1);
    }
    #pragma unroll 4
    for (int kk = 0; kk < BK; ++kk) {
      const f32x4 xv = *reinterpret_cast<const f32x4*>(&xs[buf][kk][tg * 4]);
      const f32x4 wa = *reinterpret_cast<const f32x4*>(&ws[buf][kk][cc * 4]);
      const f32x4 wb = *reinterpret_cast<const f32x4*>(&ws[buf][kk][64 + cc * 4]);
      f32x2 xp[2];
      xp[0][0] = xv[0]; xp[0][1] = xv[1];
      xp[1][0] = xv[2]; xp[1][1] = xv[3];
      const float wr[8] = {wa[0], wa[1], wa[2], wa[3], wb[0], wb[1], wb[2], wb[3]};
      #pragma unroll
      for (int p = 0; p < 2; ++p)
        #pragma unroll
        for (int j = 0; j < 8; ++j) {
          f32x2 wv = {wr[j], wr[j]};
          acc[p][j] = __builtin_elementwise_fma(xp[p], wv, acc[p][j]);
        }
    }
    if (kt < D / BK - 1) commit_x(nb, kt + 1);
    __syncthreads();
    buf = nb;
  }

  #pragma unroll
  for (int j = 0; j < 8; ++j) {
    const int col = (j < 4) ? (cc * 4 + j) : (60 + cc * 4 + j);
    const float A  = g1[col] / sqrtf(v1[col] + EPS);
    const float Bc = (b1[col] - m1[col]) * A + be1[col];
    float4 hv;
    hv.x = fmaxf(0.f, fmaf(acc[0][j][0], A, Bc));
    hv.y = fmaxf(0.f, fmaf(acc[0][j][1], A, Bc));
    hv.z = fmaxf(0.f, fmaf(acc[1][j][0], A, Bc));
    hv.w = fmaxf(0.f, fmaf(acc[1][j][1], A, Bc));
    *reinterpret_cast<float4*>(&h1s[col][tg * 4]) = hv;
  }
  __syncthreads();

  {
    const int c2 = (tid & 7) * 4;
    const int t2 = (tid >> 3) * 2;
    f32x2 a2[4];
    #pragma unroll
    for (int c = 0; c < 4; ++c) a2[c] = (f32x2)0.f;
    #pragma unroll 8
    for (int j = 0; j < 128; ++j) {
      const f32x2 h = *reinterpret_cast<const f32x2*>(&h1s[j][t2]);
      const float4 w = *reinterpret_cast<const float4*>(&W2[j * 32 + c2]);
      const float wr[4] = {w.x, w.y, w.z, w.w};
      #pragma unroll
      for (int c = 0; c < 4; ++c) {
        f32x2 wv = {wr[c], wr[c]};
        a2[c] = __builtin_elementwise_fma(h, wv, a2[c]);
      }
    }
    #pragma unroll
    for (int c = 0; c < 4; ++c) {
      const int col = c2 + c;
      const float A  = g2[col] / sqrtf(v2[col] + EPS);
      const float Bc = (b2[col] - m2[col]) * A + be2[col];
      f32x2 hv;
      hv[0] = fmaxf(0.f, fmaf(a2[c][0], A, Bc));
      hv[1] = fmaxf(0.f, fmaf(a2[c][1], A, Bc));
      *reinterpret_cast<f32x2*>(&h2s[col][t2]) = hv;
    }
  }
  __syncthreads();

  if (tid < TM) {
    float logit = b3[0];
    #pragma unroll
    for (int k = 0; k < 32; ++k)
      logit = fmaf(h2s[k][tid], W3[k], logit);
    idx_out[t0 + tid] = (logit > 0.f) ? 1 : 0;
  }
}

// ---------------- expert GEMM v3: depth-3 counted-vmcnt pipeline ------------
// 4 LDS buffers (72 KB, 2 blocks/CU). Per K-step: s_waitcnt vmcnt(2*ops_w)
// (tile kt landed; kt+1,kt+2 in flight) + raw s_barrier, then stage tile kt+3
// into the buffer last read at kt-1 (safe: barrier at kt implies compute(kt-1)
// done in all waves). Epilogue idx/b_exp loads hoisted BEFORE the pipeline and
// drained, so vmcnt counts only staging ops. XCD-affine swizzle: each XCD owns
// 32 token panels (4 MB of xb -> L2-resident across its 9 p-tiles).
__global__ __launch_bounds__(256) void expert_gemm_kernel(
    const unsigned short* __restrict__ xb,   // [TOK][D] bf16 bits
    const unsigned short* __restrict__ WT,   // [2][P][D] bf16 bits
    const float* __restrict__ b_exp,         // [2][P]
    const int* __restrict__ idx,             // [TOK]
    float* __restrict__ out)                 // [TOK][P]
{
  constexpr int GM = 128, GN = 80, GK = 32;
  constexpr int NT = D / GK;                       // 16 K-steps
  __shared__ __align__(16) unsigned short As[4][GM * GK];      // 4 x 8 KB
  __shared__ __align__(16) unsigned short Bs[4][2 * GN * GK];  // 4 x 10 KB

  const int tid  = threadIdx.x;
  const int wave = tid >> 6;
  const int lane = tid & 63;

  // XCD-affine block swizzle: 2304 blocks = 8 XCDs x (32 trows x 9 ptiles)
  const int wg    = blockIdx.x;
  const int xcd   = wg & 7;
  const int local = wg >> 3;                       // 0..287
  const int t0 = (xcd * 32 + local / 9) * GM;
  const int p0 = (local % 9) * GN;

  const int col = lane & 15;
  const int rg  = lane >> 4;

  // ---- epilogue data loaded up front (keeps loop vmcnt counts exact) ----
  int er[2][4];
  #pragma unroll
  for (int mf = 0; mf < 2; ++mf)
    #pragma unroll
    for (int j = 0; j < 4; ++j)
      er[mf][j] = idx[t0 + wave * 32 + mf * 16 + rg * 4 + j];
  float be0[5], be1v[5];
  #pragma unroll
  for (int nf = 0; nf < 5; ++nf) {
    be0[nf]  = b_exp[p0 + nf * 16 + col];
    be1v[nf] = b_exp[P + p0 + nf * 16 + col];
  }
  asm volatile("s_waitcnt vmcnt(0)" ::: "memory");

  f32x4 acc[2][2][5];
  #pragma unroll
  for (int e = 0; e < 2; ++e)
    #pragma unroll
    for (int mf = 0; mf < 2; ++mf)
      #pragma unroll
      for (int nf = 0; nf < 5; ++nf) acc[e][mf][nf] = (f32x4)(0.f);

  // staging geometry: one wave-op = 1024 B = 16 rows of 64 B
  // chunk map: c = wave + i*4, c<18  -> waves 0,1: 5 ops; waves 2,3: 4 ops
  const int srow = lane >> 2;
  const int sswz = (lane & 3) ^ ((srow >> 1) & 3);

  auto stage = [&](int b, int kt) {
    const int k0 = kt * GK;
    #pragma unroll
    for (int i = 0; i < 5; ++i) {
      const int c = wave + i * 4;
      if (c < 18) {
        if (c < 8) {                                   // A: 8 chunks
          const int row = c * 16 + srow;
          g2lds16(xb + (size_t)(t0 + row) * D + k0 + sswz * 8,
                  (char*)As[b] + c * 1024);
        } else {                                       // B: 2 experts x 5 chunks
          const int cb = c - 8;
          const int e  = (cb >= 5) ? 1 : 0;
          const int bc = cb - e * 5;
          const int pr = bc * 16 + srow;
          g2lds16(WT + ((size_t)e * P + p0 + pr) * D + k0 + sswz * 8,
                  (char*)Bs[b] + e * 5120 + bc * 1024);
        }
      }
    }
  };

  stage(0, 0);
  stage(1, 1);
  stage(2, 2);

  for (int kt = 0; kt < NT; ++kt) {
    // tile kt complete when only the (up to) 2 newer tiles remain in flight
    if (wave < 2) asm volatile("s_waitcnt vmcnt(10)" ::: "memory");
    else          asm volatile("s_waitcnt vmcnt(8)"  ::: "memory");
    __builtin_amdgcn_s_barrier();
    __builtin_amdgcn_sched_barrier(0);

    if (kt + 3 < NT) stage((kt + 3) & 3, kt + 3);

    const int buf = kt & 3;
    bf16x8 af[2];
    #pragma unroll
    for (int mf = 0; mf < 2; ++mf) {
      const int r  = wave * 32 + mf * 16 + (lane & 15);
      const int ch = (lane >> 4) ^ ((r >> 1) & 3);
      af[mf] = *(const bf16x8*)((const char*)As[buf] + r * 64 + ch * 16);
    }
    #pragma unroll
    for (int e = 0; e < 2; ++e) {
      #pragma unroll
      for (int nf = 0; nf < 5; ++nf) {
        const int pr = nf * 16 + (lane & 15);
        const int ch = (lane >> 4) ^ ((pr >> 1) & 3);
        bf16x8 bfrag = *(const bf16x8*)((const char*)Bs[buf] + e * 5120 + pr * 64 + ch * 16);
        #pragma unroll
        for (int mf = 0; mf < 2; ++mf)
          acc[e][mf][nf] = __builtin_amdgcn_mfma_f32_16x16x32_bf16(
              af[mf], bfrag, acc[e][mf][nf], 0, 0, 0);
      }
    }
  }

  // epilogue: per-row expert select + bias, store fp32
  #pragma unroll
  for (int nf = 0; nf < 5; ++nf) {
    const int p = p0 + nf * 16 + col;
    #pragma unroll
    for (int mf = 0; mf < 2; ++mf) {
      #pragma unroll
      for (int j = 0; j < 4; ++j) {
        const int row = wave * 32 + mf * 16 + rg * 4 + j;
        const float v = er[mf][j] ? (acc[1][mf][nf][j] + be1v[nf])
                                  : (acc[0][mf][nf][j] + be0[nf]);
        out[(size_t)(t0 + row) * P + p] = v;
      }
    }
  }
}

extern "C" void kernel_launch(void* const* d_in, const int* in_sizes, int n_in,
                              void* d_out, int out_size, void* d_ws, size_t ws_size,
                              hipStream_t stream) {
  const float* x     = (const float*)d_in[0];
  const float* W_exp = (const float*)d_in[1];
  const float* b_exp = (const float*)d_in[2];
  const float* W1 = (const float*)d_in[3];
  const float* b1 = (const float*)d_in[4];
  const float* g1 = (const float*)d_in[5];
  const float* be1 = (const float*)d_in[6];
  const float* m1 = (const float*)d_in[7];
  const float* v1 = (const float*)d_in[8];
  const float* W2 = (const float*)d_in[9];
  const float* b2 = (const float*)d_in[10];
  const float* g2 = (const float*)d_in[11];
  const float* be2 = (const float*)d_in[12];
  const float* m2 = (const float*)d_in[13];
  const float* v2 = (const float*)d_in[14];
  const float* W3 = (const float*)d_in[15];
  const float* b3 = (const float*)d_in[16];
  float* out = (float*)d_out;

  unsigned short* xb = (unsigned short*)d_ws;                       // 32 MB
  unsigned short* WT = (unsigned short*)((char*)d_ws + (size_t)TOK * D * 2);
  int* idx = (int*)((char*)d_ws + (size_t)TOK * D * 2 + (size_t)2 * P * D * 2);

  hipLaunchKernelGGL(wconv_kernel, dim3(D / 16, P / 16, 2), dim3(16, 16),
                     0, stream, W_exp, WT);
  hipLaunchKernelGGL(classifier_kernel, dim3(TOK / 64), dim3(256), 0, stream,
                     x, W1, b1, g1, be1, m1, v1, W2, b2, g2, be2, m2, v2, W3, b3,
                     xb, idx);
  hipLaunchKernelGGL(expert_gemm_kernel, dim3((TOK / 128) * (P / 80)), dim3(256),
                     0, stream, xb, WT, b_exp, idx, out);
}